// Round 5
// baseline (13907.735 us; speedup 1.0000x reference)
//
#include <hip/hip_runtime.h>
#include <hip/hip_bf16.h>

// ---------------------------------------------------------------------------
// 3-layer LSTM (TF LSTMCell, gates i,j,f,o, forget_bias=1) + 3 heads.
// B=256, S=128, F=128, H=400, 4H=1600.
//
// v2: recurrence = one block per 16-row batch group (16 groups, 832 threads,
// 13 waves). W_h entirely in VGPRs (waves 0-11: 32 units, wave 12: 16-unit
// tail). h ping-pongs in LDS; the only per-step sync is __syncthreads().
// preZ double-buffer prefetched into LDS via global_load_lds, overlapped
// with the MFMA phase. No fences / flags / cross-CU traffic (v1's 35us/step
// was agent-scope wbl2/inv cache maintenance).
//
// Workspace layout (total 173,105,152 B):
//   xbf   @ 0          :  8,388,608  B
//   HA    @ 8388608    : 26,214,400  B
//   HB    @ 34603008   : 26,214,400  B
//   preZ  @ 60817408   : 104,857,600 B  ([32768][1600] bf16)
//   wfrag @ 165675008  : 3,276,800   B  (GEMM B fragments, 3 layers)
//   rfrag @ 168951808  : 4,153,344   B  (recurrent W_h fragments, 3 layers)
// ---------------------------------------------------------------------------

typedef __attribute__((ext_vector_type(8))) short bf16x8;  // 8 bf16 = 4 VGPR
typedef __attribute__((ext_vector_type(4))) float f32x4;

#define S_LEN 128
#define HID   400
#define NCOL  1600
#define WS_NEEDED 173105152ull

__device__ __forceinline__ f32x4 mfma16(bf16x8 a, bf16x8 b, f32x4 c) {
  return __builtin_amdgcn_mfma_f32_16x16x32_bf16(a, b, c, 0, 0, 0);
}
__device__ __forceinline__ void gll16(const void* g, void* l) {
  __builtin_amdgcn_global_load_lds(
      (const __attribute__((address_space(1))) void*)g,
      (__attribute__((address_space(3))) void*)l, 16, 0, 0);
}
__device__ __forceinline__ float bf2f(__hip_bfloat16 h) { return __bfloat162float(h); }
__device__ __forceinline__ __hip_bfloat16 f2bf(float f) { return __float2bfloat16(f); }
__device__ __forceinline__ float sigm(float x) { return 1.f / (1.f + __expf(-x)); }
__device__ __forceinline__ float tanh_fast(float x) { return 1.f - 2.f / (__expf(2.f * x) + 1.f); }
__device__ __forceinline__ float ldbf(const char* p) {
  const unsigned short u = *(const unsigned short*)p;
  return __builtin_bit_cast(float, (unsigned)u << 16);
}

// ---------------------------------------------------------------- cvt x->bf16
__global__ __launch_bounds__(256) void cvt_x_kernel(const float* __restrict__ x,
                                                    __hip_bfloat16* __restrict__ xbf) {
  const int i = blockIdx.x * 256 + threadIdx.x;  // 1,048,576 float4s exactly
  float4 v = ((const float4*)x)[i];
  ushort4 u;
  u.x = __builtin_bit_cast(unsigned short, f2bf(v.x));
  u.y = __builtin_bit_cast(unsigned short, f2bf(v.y));
  u.z = __builtin_bit_cast(unsigned short, f2bf(v.z));
  u.w = __builtin_bit_cast(unsigned short, f2bf(v.w));
  ((ushort4*)xbf)[i] = u;
}

// ---------------------------------------------- weight prep: GEMM B fragments
// wfrag chunks: L0 kt0..3 (K=128), L1 kt0..13 (K=448 pad0), L2 kt0..13.
// chunk(kt,nt) = 64 lanes x 8 bf16; lane l holds W[kt*32+(l>>4)*8+j][nt*16+(l&15)]
__global__ __launch_bounds__(256) void prep_gemm_frag(
    const float* __restrict__ K0, const float* __restrict__ K1,
    const float* __restrict__ K2, __hip_bfloat16* __restrict__ wfrag) {
  const int total = 3200 * 512;
  for (int e = blockIdx.x * 256 + threadIdx.x; e < total; e += gridDim.x * 256) {
    const int ch = e >> 9, r = e & 511;
    const int c16 = r & 15, j = (r >> 4) & 7, kg = r >> 7;
    const float* W; int Kv, chL;
    if (ch < 400)       { W = K0; Kv = 128; chL = ch; }
    else if (ch < 1800) { W = K1; Kv = 400; chL = ch - 400; }
    else                { W = K2; Kv = 400; chL = ch - 1800; }
    const int kt = chL / 100, nt = chL - kt * 100;
    const int k = kt * 32 + kg * 8 + j;
    const float v = (k < Kv) ? W[(long)k * NCOL + nt * 16 + c16] : 0.f;
    wfrag[(ch << 9) + ((kg * 16 + c16) << 3) + j] = f2bf(v);
  }
}

// ------------------------------------------- weight prep: recurrent fragments
// Layout per layer: chunk ch = ((w*4 + q)*2 + ut)*13 + kt, 1024 B each.
// Lane l of chunk holds 8 bf16: W_h[kt*32+(l>>4)*8+j][q*400 + w*32 + ut*16 + (l&15)]
// (zero-padded where k>=400 or unit>=400). 1352 chunks/layer = 1,384,448 B.
__global__ __launch_bounds__(256) void prep_rec_frag(
    const float* __restrict__ K0, const float* __restrict__ K1,
    const float* __restrict__ K2, __hip_bfloat16* __restrict__ rfrag) {
  const int perL = 1352 * 512;  // 692,224 elems
  const int total = 3 * perL;
  for (int e = blockIdx.x * 256 + threadIdx.x; e < total; e += gridDim.x * 256) {
    const int l = e / perL, eL = e - l * perL;
    const int ch = eL >> 9, r = eL & 511;
    const int lane = r >> 3, j = r & 7;
    const int kt = ch % 13;
    int c2 = ch / 13;
    const int ut = c2 & 1; c2 >>= 1;
    const int q = c2 & 3;  const int w = c2 >> 2;
    const int unit = w * 32 + ut * 16 + (lane & 15);
    const int k = kt * 32 + ((lane >> 4) << 3) + j;
    const float* W = (l == 0) ? K0 : ((l == 1) ? K1 : K2);
    const int D = (l == 0) ? 128 : 400;
    const float v = (k < HID && unit < HID) ? W[(long)(D + k) * NCOL + q * 400 + unit] : 0.f;
    rfrag[(long)l * perL + (ch << 9) + (lane << 3) + j] = f2bf(v);
  }
}

// ------------------------------------------------------------- preZ GEMM
// C[32768][1600] bf16 = A[32768][lda] bf16 @ Wfrag + bias. 128x128 tile,
// BK=64, 4 waves (2x2), fragment-linear LDS staged via global_load_lds x16.
__global__ __launch_bounds__(256) void gemm_kernel(
    const __hip_bfloat16* __restrict__ A, int lda, int kIters,
    const __hip_bfloat16* __restrict__ wfrag, const float* __restrict__ bias,
    __hip_bfloat16* __restrict__ C) {
  __shared__ uint4 lds4[32 * 64];  // 32 KiB: chunks 0-15 A, 16-31 B
  char* lds = (char*)lds4;
  const int tid = threadIdx.x;
  const int wave = tid >> 6, lane = tid & 63;
  const int wm = wave >> 1, wn = wave & 1;
  const int m0 = blockIdx.x << 7, n0 = blockIdx.y << 7;

  f32x4 acc[4][4];
#pragma unroll
  for (int i = 0; i < 4; ++i)
#pragma unroll
    for (int j = 0; j < 4; ++j) acc[i][j] = (f32x4){0.f, 0.f, 0.f, 0.f};

  for (int it = 0; it < kIters; ++it) {
    const int k0 = it << 6;
#pragma unroll
    for (int q = 0; q < 8; ++q) {
      const int id = wave * 8 + q;
      char* dst = lds + (id << 10);
      if (id < 16) {  // A chunk (kk, mt)
        const int kk = id >> 3, mt = id & 7;
        const int m = m0 + mt * 16 + (lane & 15);
        int k = k0 + kk * 32 + ((lane >> 4) << 3);
        if (k + 8 > lda) k = 0;  // garbage x zero-B is safe
        gll16((const char*)A + (((long)m * lda + k) << 1), dst);
      } else {        // B chunk (kk, nt)
        const int kk = (id >> 3) & 1, nt = id & 7;
        const int ktg = (it << 1) + kk;
        int ntg = (n0 >> 4) + nt;
        if (ntg > 99) ntg = 99;  // results discarded by store guard
        gll16((const char*)wfrag + ((((ktg * 100 + ntg) << 6) + lane) << 4), dst);
      }
    }
    asm volatile("s_waitcnt vmcnt(0)" ::: "memory");
    __syncthreads();
#pragma unroll
    for (int kk = 0; kk < 2; ++kk) {
      bf16x8 af[4], bfr[4];
#pragma unroll
      for (int i = 0; i < 4; ++i) {
        af[i]  = *(const bf16x8*)(lds + ((kk * 8 + wm * 4 + i) << 10) + (lane << 4));
        bfr[i] = *(const bf16x8*)(lds + ((16 + kk * 8 + wn * 4 + i) << 10) + (lane << 4));
      }
#pragma unroll
      for (int i = 0; i < 4; ++i)
#pragma unroll
        for (int j = 0; j < 4; ++j) acc[i][j] = mfma16(af[i], bfr[j], acc[i][j]);
    }
    __syncthreads();
  }
  const int rowbase = m0 + wm * 64 + ((lane >> 4) << 2);
  const int colbase = n0 + wn * 64 + (lane & 15);
#pragma unroll
  for (int j = 0; j < 4; ++j) {
    const int col = colbase + j * 16;
    if (col < NCOL) {
      const float bs = bias[col];
#pragma unroll
      for (int i = 0; i < 4; ++i) {
        const int row = rowbase + i * 16;
#pragma unroll
        for (int r = 0; r < 4; ++r)
          C[(long)(row + r) * NCOL + col] = f2bf(acc[i][j][r] + bs);
      }
    }
  }
}

// ------------------------------------------------------------- recurrence v2
// One block per group of 16 batch rows. 832 threads = 13 waves.
// Wave w<12: units [32w, 32w+32) (2 MFMA N-tiles x 4 gates); wave 12: units
// [384,400) (1 N-tile). W_h fragments stationary in VGPRs (up to 416/lane).
// LDS: pz double buffer 2x[16][1600] bf16 (51,200 B each) + h ping-pong
// 2x[16][424] bf16 (13,568 B each) = 129,536 B.
__device__ __forceinline__ void stage_pz(const __hip_bfloat16* __restrict__ preZ,
                                         int G, int t, char* dstbase,
                                         int tid, int wv) {
#pragma unroll
  for (int it = 0; it < 4; ++it) {
    const int s = it * 832 + tid;
    if (s < 3200) {                     // wave-uniform guard (3200 = 50 waves)
      const int row = s / 200;          // 0..15
      const int off = s - row * 200;    // 0..199 (16B units)
      const long gb = ((long)((G * 16 + row) * 128 + t)) * 3200 + (long)off * 16;
      gll16((const char*)preZ + gb, dstbase + (it * 832 + (wv << 6)) * 16);
    }
  }
}

__global__ __launch_bounds__(832, 1) void rec2_kernel(
    const __hip_bfloat16* __restrict__ rfragL,
    const __hip_bfloat16* __restrict__ preZ,
    __hip_bfloat16* __restrict__ Hout) {
  __shared__ __attribute__((aligned(16))) char smem[129536];
  char* const pz0 = smem;
  char* const pz1 = smem + 51200;
  char* const h0  = smem + 102400;
  char* const h1  = smem + 102400 + 13568;

  const int tid = threadIdx.x;
  const int wv = tid >> 6, lane = tid & 63;
  const int l15 = lane & 15, l4 = lane >> 4;
  const int G = blockIdx.x;

  // zero both h buffers (incl pad cols 400..423): 27,136 B = 6784 u32
  for (int s = tid; s < 6784; s += 832) ((unsigned*)h0)[s] = 0;

  // stage pz(t=0) into pz0
  stage_pz(preZ, G, 0, pz0, tid, wv);

  // stationary W_h fragments -> VGPRs
  bf16x8 Bw[4][2][13];
  {
    const uint4* rp = (const uint4*)rfragL;
#pragma unroll
    for (int q = 0; q < 4; ++q)
#pragma unroll
      for (int ut = 0; ut < 2; ++ut)
#pragma unroll
        for (int kt = 0; kt < 13; ++kt)
          Bw[q][ut][kt] = __builtin_bit_cast(
              bf16x8, rp[((((wv * 4 + q) * 2 + ut) * 13) + kt) * 64 + lane]);
  }

  float cs[2][4];
#pragma unroll
  for (int ut = 0; ut < 2; ++ut)
#pragma unroll
    for (int r = 0; r < 4; ++r) cs[ut][r] = 0.f;

  const int hrow = l15 * 424 * 2;  // byte base of this lane's A row
  __syncthreads();  // drains zeroing (lgkm) + pz(0) staging (vmcnt)

  for (int t = 0; t < S_LEN; ++t) {
    const int p = t & 1;
    // prefetch next step's preZ; hidden under this step's MFMA+gate phases
    if (t + 1 < S_LEN) stage_pz(preZ, G, t + 1, p ? pz0 : pz1, tid, wv);

    const char* hc = p ? h1 : h0;
    f32x4 acc[4][2];
#pragma unroll
    for (int q = 0; q < 4; ++q) {
      acc[q][0] = (f32x4){0.f, 0.f, 0.f, 0.f};
      acc[q][1] = (f32x4){0.f, 0.f, 0.f, 0.f};
    }
    if (wv < 12) {
#pragma unroll
      for (int kt = 0; kt < 13; ++kt) {
        const bf16x8 a = *(const bf16x8*)(hc + hrow + ((kt * 32 + (l4 << 3)) << 1));
#pragma unroll
        for (int q = 0; q < 4; ++q) {
          acc[q][0] = mfma16(a, Bw[q][0][kt], acc[q][0]);
          acc[q][1] = mfma16(a, Bw[q][1][kt], acc[q][1]);
        }
      }
    } else {
#pragma unroll
      for (int kt = 0; kt < 13; ++kt) {
        const bf16x8 a = *(const bf16x8*)(hc + hrow + ((kt * 32 + (l4 << 3)) << 1));
#pragma unroll
        for (int q = 0; q < 4; ++q)
          acc[q][0] = mfma16(a, Bw[q][0][kt], acc[q][0]);
      }
    }

    // gate phase: i,j,f,o for this lane's (row,unit) pairs are lane-local
    const char* pzc = p ? pz1 : pz0;
    char* hn = p ? h0 : h1;
    const int tOff = t * 400;
#define GATE_UT(UT)                                                           \
    {                                                                         \
      const int unit = wv * 32 + (UT)*16 + l15;                               \
      _Pragma("unroll")                                                       \
      for (int r = 0; r < 4; ++r) {                                           \
        const int row = l4 * 4 + r;                                           \
        const char* pzp = pzc + row * 3200 + unit * 2;                        \
        const float zi = acc[0][UT][r] + ldbf(pzp);                           \
        const float zj = acc[1][UT][r] + ldbf(pzp + 800);                     \
        const float zf = acc[2][UT][r] + ldbf(pzp + 1600) + 1.f;              \
        const float zo = acc[3][UT][r] + ldbf(pzp + 2400);                    \
        const float cn = cs[UT][r] * sigm(zf) + sigm(zi) * tanh_fast(zj);     \
        cs[UT][r] = cn;                                                       \
        const float hv = tanh_fast(cn) * sigm(zo);                            \
        const unsigned short hb = __builtin_bit_cast(unsigned short, f2bf(hv)); \
        *(unsigned short*)(hn + ((row * 424 + unit) << 1)) = hb;              \
        Hout[(long)G * 819200 + row * 51200 + tOff + unit] =                  \
            __builtin_bit_cast(__hip_bfloat16, hb);                           \
      }                                                                       \
    }
    GATE_UT(0)
    if (wv < 12) GATE_UT(1)
#undef GATE_UT
    __syncthreads();  // h(t+1) visible; pz(t+1) staged; safe to flip buffers
  }
}

// ------------------------------------------------------------- output heads
__global__ __launch_bounds__(256) void heads_kernel(
    const __hip_bfloat16* __restrict__ H, const float* __restrict__ wlg,
    const float* __restrict__ blg, const float* __restrict__ wsm2,
    const float* __restrict__ bsm2, const float* __restrict__ w5,
    const float* __restrict__ b5, float* __restrict__ out) {
  __shared__ float wc[8][400];
  const int tid = threadIdx.x;
  for (int e = tid; e < 3200; e += 256) {
    const int cc = e / 400, k = e - cc * 400;
    float v;
    if (cc == 0) v = wlg[k];
    else if (cc <= 2) v = wsm2[k * 2 + (cc - 1)];
    else v = w5[k * 5 + (cc - 3)];
    wc[cc][k] = v;
  }
  __syncthreads();
  const int wave = tid >> 6, lane = tid & 63;
  const int row = blockIdx.x * 4 + wave;
  const __hip_bfloat16* hrow = H + (long)row * HID;
  float pacc[8] = {0.f, 0.f, 0.f, 0.f, 0.f, 0.f, 0.f, 0.f};
  for (int k = lane; k < HID; k += 64) {
    const float hv = bf2f(hrow[k]);
#pragma unroll
    for (int cc = 0; cc < 8; ++cc) pacc[cc] += hv * wc[cc][k];
  }
#pragma unroll
  for (int cc = 0; cc < 8; ++cc)
    for (int off = 32; off > 0; off >>= 1)
      pacc[cc] += __shfl_xor(pacc[cc], off, 64);
  if (lane == 0) {
    const float o0 = sigm(pacc[0] + blg[0]);
    const float z1 = pacc[1] + bsm2[0], z2 = pacc[2] + bsm2[1];
    const float mm = fmaxf(z1, z2);
    const float e1 = __expf(z1 - mm), e2 = __expf(z2 - mm);
    const float inv2 = 1.f / (e1 + e2);
    float z5[5], m5 = -1e30f;
#pragma unroll
    for (int c = 0; c < 5; ++c) { z5[c] = pacc[3 + c] + b5[c]; m5 = fmaxf(m5, z5[c]); }
    float es[5], s5 = 0.f;
#pragma unroll
    for (int c = 0; c < 5; ++c) { es[c] = __expf(z5[c] - m5); s5 += es[c]; }
    const float inv5 = 1.f / s5;
    float4* op = (float4*)(out + (long)row * 8);
    op[0] = make_float4(o0, e1 * inv2, e2 * inv2, es[0] * inv5);
    op[1] = make_float4(es[1] * inv5, es[2] * inv5, es[3] * inv5, es[4] * inv5);
  }
}

// ---------------------------------------------------------------------------
extern "C" void kernel_launch(void* const* d_in, const int* in_sizes, int n_in,
                              void* d_out, int out_size, void* d_ws, size_t ws_size,
                              hipStream_t stream) {
  (void)in_sizes; (void)n_in; (void)out_size;
  if (ws_size < WS_NEEDED) return;  // fail clean rather than scribble OOB

  const float* x    = (const float*)d_in[0];
  const float* K0   = (const float*)d_in[1];
  const float* B0   = (const float*)d_in[2];
  const float* K1   = (const float*)d_in[3];
  const float* B1   = (const float*)d_in[4];
  const float* K2   = (const float*)d_in[5];
  const float* B2   = (const float*)d_in[6];
  const float* wlg  = (const float*)d_in[7];
  const float* blg  = (const float*)d_in[8];
  const float* wsm2 = (const float*)d_in[9];
  const float* bsm2 = (const float*)d_in[10];
  const float* w5   = (const float*)d_in[11];
  const float* b5   = (const float*)d_in[12];
  float* out = (float*)d_out;
  char* ws = (char*)d_ws;

  __hip_bfloat16* xbf   = (__hip_bfloat16*)(ws + 0);
  __hip_bfloat16* HA    = (__hip_bfloat16*)(ws + 8388608);
  __hip_bfloat16* HB    = (__hip_bfloat16*)(ws + 34603008);
  __hip_bfloat16* preZ  = (__hip_bfloat16*)(ws + 60817408);
  __hip_bfloat16* wfrag = (__hip_bfloat16*)(ws + 165675008);
  __hip_bfloat16* rfrag = (__hip_bfloat16*)(ws + 168951808);

  cvt_x_kernel<<<4096, 256, 0, stream>>>(x, xbf);
  prep_gemm_frag<<<2048, 256, 0, stream>>>(K0, K1, K2, wfrag);
  prep_rec_frag<<<2048, 256, 0, stream>>>(K0, K1, K2, rfrag);

  // layer 0
  gemm_kernel<<<dim3(256, 13), 256, 0, stream>>>(xbf, 128, 2, wfrag, B0, preZ);
  rec2_kernel<<<16, 832, 0, stream>>>(rfrag, preZ, HA);

  // layer 1
  gemm_kernel<<<dim3(256, 13), 256, 0, stream>>>(HA, 400, 7, wfrag + 204800, B1, preZ);
  rec2_kernel<<<16, 832, 0, stream>>>(rfrag + 692224, preZ, HB);

  // layer 2
  gemm_kernel<<<dim3(256, 13), 256, 0, stream>>>(HB, 400, 7, wfrag + 921600, B2, preZ);
  rec2_kernel<<<16, 832, 0, stream>>>(rfrag + 1384448, preZ, HA);

  // heads (layer-2 output is in HA)
  heads_kernel<<<8192, 256, 0, stream>>>(HA, wlg, blg, wsm2, bsm2, w5, b5, out);
}